// Round 1
// baseline (198.925 us; speedup 1.0000x reference)
//
#include <hip/hip_runtime.h>

// JointNetwork collapse:
//   out[b,t,u,v] = ((enc[b,t]+pred[b,u])@W0 + b0)@W1 + b1
//                = ye[b,t,v] + yp[b,u,v]
// where ye = enc@W0@W1 (no biases), yp = (pred@W0 + b0)@W1 + b1.
// Two tiny fp32 GEMMs (rows: 1024 enc + 256 pred = 1280) + one 536MB broadcast-add.

#define BM 64
#define BN 64
#define BK 16
#define LDSS 68   // padded LDS stride (68*4B = 272B, 16B-aligned, breaks pow2 bank pattern)

__global__ __launch_bounds__(256) void gemm_bias(
    const float* __restrict__ A0, const float* __restrict__ A1, int rows0,
    const float* __restrict__ Bmat, const float* __restrict__ bias,
    float* __restrict__ C, int N, int K, int biasRowStart)
{
    __shared__ float As[BK][LDSS];  // transposed: As[k][m]
    __shared__ float Bs[BK][LDSS];  // Bs[k][n]

    const int tid = threadIdx.x;
    const int tx = tid & 15;        // output col group
    const int ty = tid >> 4;        // output row group
    const int row0 = blockIdx.y * BM;
    const int col0 = blockIdx.x * BN;

    // Tiles never straddle the A0/A1 boundary (rows0 % BM == 0).
    const float* A = (row0 < rows0) ? (A0 + (size_t)row0 * K)
                                    : (A1 + (size_t)(row0 - rows0) * K);

    const int la_row = tid >> 2;        // 0..63  (m within tile)
    const int la_k4  = (tid & 3) << 2;  // 0,4,8,12
    const int lb_k   = tid >> 4;        // 0..15
    const int lb_n4  = (tid & 15) << 2; // 0..60

    float acc[4][4] = {};

    for (int k0 = 0; k0 < K; k0 += BK) {
        float4 av = *reinterpret_cast<const float4*>(A + (size_t)la_row * K + k0 + la_k4);
        float4 bv = *reinterpret_cast<const float4*>(Bmat + (size_t)(k0 + lb_k) * N + col0 + lb_n4);
        __syncthreads();  // prior iter's LDS reads done before overwrite
        As[la_k4 + 0][la_row] = av.x;
        As[la_k4 + 1][la_row] = av.y;
        As[la_k4 + 2][la_row] = av.z;
        As[la_k4 + 3][la_row] = av.w;
        *reinterpret_cast<float4*>(&Bs[lb_k][lb_n4]) = bv;
        __syncthreads();
        #pragma unroll
        for (int kk = 0; kk < BK; ++kk) {
            float4 a = *reinterpret_cast<const float4*>(&As[kk][ty << 2]);
            float4 b = *reinterpret_cast<const float4*>(&Bs[kk][tx << 2]);
            float af[4] = {a.x, a.y, a.z, a.w};
            float bf[4] = {b.x, b.y, b.z, b.w};
            #pragma unroll
            for (int i = 0; i < 4; ++i)
                #pragma unroll
                for (int j = 0; j < 4; ++j)
                    acc[i][j] = fmaf(af[i], bf[j], acc[i][j]);
        }
    }

    const bool doBias = (row0 >= biasRowStart);
    #pragma unroll
    for (int i = 0; i < 4; ++i) {
        const int r = row0 + (ty << 2) + i;
        const int c = col0 + (tx << 2);
        float4 v = make_float4(acc[i][0], acc[i][1], acc[i][2], acc[i][3]);
        if (doBias) {
            v.x += bias[c];
            v.y += bias[c + 1];
            v.z += bias[c + 2];
            v.w += bias[c + 3];
        }
        *reinterpret_cast<float4*>(C + (size_t)r * N + c) = v;
    }
}

// out[((b*T+t)*U+u)*V + v] = ye[(b*T+t)*V + v] + yp[(b*U+u)*V + v]
// In float4 units: V4=256 (shift 8), U=128 (shift 7), T=512 (shift 9).
__global__ __launch_bounds__(256) void bcast_add(
    const float4* __restrict__ ye, const float4* __restrict__ yp,
    float4* __restrict__ out, long n4)
{
    long i = (long)blockIdx.x * blockDim.x + threadIdx.x;
    const long stride = (long)gridDim.x * blockDim.x;
    for (; i < n4; i += stride) {
        const int v4 = (int)(i & 255);
        const long r = i >> 8;            // (b*T + t)*U + u
        const int u = (int)(r & 127);
        const long bt = r >> 7;           // b*T + t
        const int b = (int)(bt >> 9);
        const long ye_i = (bt << 8) | v4;
        const long yp_i = ((((long)b << 7) | u) << 8) | v4;
        float4 a = ye[ye_i];
        float4 c = yp[yp_i];
        a.x += c.x; a.y += c.y; a.z += c.z; a.w += c.w;
        out[i] = a;
    }
}

extern "C" void kernel_launch(void* const* d_in, const int* in_sizes, int n_in,
                              void* d_out, int out_size, void* d_ws, size_t ws_size,
                              hipStream_t stream)
{
    const float* pred = (const float*)d_in[0];  // [2,128,512]
    const float* enc  = (const float*)d_in[1];  // [2,512,512]
    const float* W0   = (const float*)d_in[2];  // [512,512]
    const float* b0   = (const float*)d_in[3];  // [512]
    const float* W1   = (const float*)d_in[4];  // [512,1024]
    const float* b1   = (const float*)d_in[5];  // [1024]
    float* out = (float*)d_out;                 // [2,512,128,1024] fp32

    const int BT = 1024;      // B*T rows (enc)
    const int Mrows = 1280;   // B*T + B*U
    const int D = 512, H = 512, V = 1024;

    float* Hbuf = (float*)d_ws;                 // [1280][512]  = 2.62 MB
    float* Ybuf = Hbuf + (size_t)Mrows * H;     // [1280][1024] = 5.24 MB

    // H = [enc; pred] @ W0, bias b0 only on pred rows (>= 1024)
    gemm_bias<<<dim3(H / BN, Mrows / BM), 256, 0, stream>>>(
        enc, pred, BT, W0, b0, Hbuf, H, D, BT);

    // Y = H @ W1, bias b1 only on pred rows (>= 1024)
    gemm_bias<<<dim3(V / BN, Mrows / BM), 256, 0, stream>>>(
        Hbuf, Hbuf + (size_t)BT * H, BT, W1, b1, Ybuf, V, H, BT);

    // out = ye broadcast+ yp   (536 MB write)
    const long n4 = (long)2 * 512 * 128 * (V / 4);   // 33,554,432 float4
    bcast_add<<<2048, 256, 0, stream>>>(
        (const float4*)Ybuf, (const float4*)(Ybuf + (size_t)BT * V),
        (float4*)out, n4);
}

// Round 2
// 151.273 us; speedup vs baseline: 1.3150x; 1.3150x over previous
//
#include <hip/hip_runtime.h>

// out[b,t,u,v] = ye[b,t,v] + yp[b,u,v]
//   ye = enc@W0@W1 (no biases), yp = (pred@W0 + b0)@W1 + b1.
// Split-K=2 GEMMs write partials; partial-sums are folded into the consumer:
//   GEMM2 A-staging reads P0+P1 (+b0 on pred rows); finalize_yp folds Q0+Q1+b1
//   for the 256 pred rows; bcast reads finalized yp once per out element.

#define BM 64
#define BN 64
#define BK 16
#define LDSS 68   // padded LDS row stride (floats)

__device__ __forceinline__ float4 f4add(float4 a, float4 b) {
    a.x += b.x; a.y += b.y; a.z += b.z; a.w += b.w; return a;
}

// MODE 0: A rows from [A0(1024 rows); A1] raw (enc;pred).
// MODE 1: A = A0+A1 elementwise (split-K partials), +bias_k[k] for rows>=1024.
template<int MODE>
__global__ __launch_bounds__(256) void gemm_sk(
    const float* __restrict__ A0, const float* __restrict__ A1,
    const float* __restrict__ bias_k,
    const float* __restrict__ Bmat,
    float* __restrict__ C0, float* __restrict__ C1,
    int N, int K, int Kchunk)
{
    __shared__ float As[2][BK][LDSS];   // transposed: As[.][k][m]
    __shared__ float Bs[2][BK][LDSS];   // Bs[.][k][n]

    const int tid = threadIdx.x;
    const int tx = tid & 15;
    const int ty = tid >> 4;
    const int row0 = blockIdx.y * BM;
    const int col0 = blockIdx.x * BN;
    const int kbeg = blockIdx.z * Kchunk;
    const int kend = kbeg + Kchunk;
    float* __restrict__ C = blockIdx.z ? C1 : C0;

    const int la_row = tid >> 2;        // 0..63
    const int la_k4  = (tid & 3) << 2;  // 0,4,8,12
    const int lb_k   = tid >> 4;        // 0..15
    const int lb_n4  = (tid & 15) << 2; // 0..60

    auto loadA = [&](int k0) -> float4 {
        if (MODE == 0) {
            const float* Ar = (row0 < 1024)
                ? A0 + (size_t)(row0 + la_row) * K
                : A1 + (size_t)(row0 - 1024 + la_row) * K;
            return *reinterpret_cast<const float4*>(Ar + k0 + la_k4);
        } else {
            const size_t o = (size_t)(row0 + la_row) * K + k0 + la_k4;
            float4 a = f4add(*reinterpret_cast<const float4*>(A0 + o),
                             *reinterpret_cast<const float4*>(A1 + o));
            if (row0 >= 1024)   // uniform per block
                a = f4add(a, *reinterpret_cast<const float4*>(bias_k + k0 + la_k4));
            return a;
        }
    };
    auto loadB = [&](int k0) -> float4 {
        return *reinterpret_cast<const float4*>(
            Bmat + (size_t)(k0 + lb_k) * N + col0 + lb_n4);
    };
    auto stage = [&](int buf, float4 av, float4 bv) {
        As[buf][la_k4 + 0][la_row] = av.x;
        As[buf][la_k4 + 1][la_row] = av.y;
        As[buf][la_k4 + 2][la_row] = av.z;
        As[buf][la_k4 + 3][la_row] = av.w;
        *reinterpret_cast<float4*>(&Bs[buf][lb_k][lb_n4]) = bv;
    };

    float acc[4][4] = {};
    auto compute = [&](int buf) {
        #pragma unroll
        for (int kk = 0; kk < BK; ++kk) {
            float4 a = *reinterpret_cast<const float4*>(&As[buf][kk][ty << 2]);
            float4 b = *reinterpret_cast<const float4*>(&Bs[buf][kk][tx << 2]);
            float af[4] = {a.x, a.y, a.z, a.w};
            float bf[4] = {b.x, b.y, b.z, b.w};
            #pragma unroll
            for (int i = 0; i < 4; ++i)
                #pragma unroll
                for (int j = 0; j < 4; ++j)
                    acc[i][j] = fmaf(af[i], bf[j], acc[i][j]);
        }
    };

    stage(0, loadA(kbeg), loadB(kbeg));
    __syncthreads();
    int buf = 0;
    for (int k0 = kbeg + BK; k0 < kend; k0 += BK) {
        float4 av = loadA(k0);   // prefetch — latency hides under compute
        float4 bv = loadB(k0);
        compute(buf);
        stage(buf ^ 1, av, bv);  // other buffer: no sync needed before write
        __syncthreads();
        buf ^= 1;
    }
    compute(buf);

    #pragma unroll
    for (int i = 0; i < 4; ++i) {
        const int r = row0 + (ty << 2) + i;
        const int c = col0 + (tx << 2);
        *reinterpret_cast<float4*>(C + (size_t)r * N + c)
            = make_float4(acc[i][0], acc[i][1], acc[i][2], acc[i][3]);
    }
}

// ypF[(b*128+u)*256 + v4] = Q0[pred] + Q1[pred] + b1  (pred rows = 1024..1279)
__global__ __launch_bounds__(256) void finalize_yp(
    const float4* __restrict__ Q0, const float4* __restrict__ Q1,
    const float4* __restrict__ b1, float4* __restrict__ ypF)
{
    const int i = blockIdx.x * 256 + threadIdx.x;   // 0..65535
    const int v4 = i & 255;
    ypF[i] = f4add(f4add(Q0[262144 + i], Q1[262144 + i]), b1[v4]);
}

// out[(bt*128+u)*256+v4] = (Q0[bt]+Q1[bt]) + ypF[b*128+u]
// grid: 2048 blocks = (bt, u-half); 256 threads = v4. ye held in registers.
__global__ __launch_bounds__(256) void bcast_add(
    const float4* __restrict__ Q0, const float4* __restrict__ Q1,
    const float4* __restrict__ ypF, float4* __restrict__ out)
{
    const int bid = blockIdx.x;
    const int bt = bid >> 1;            // 0..1023
    const int uh = bid & 1;             // u half
    const int v4 = threadIdx.x;         // 0..255
    const int b = bt >> 9;

    const size_t ybase = ((size_t)bt << 8) + v4;
    float4 ye = f4add(Q0[ybase], Q1[ybase]);

    const float4* yp = ypF + ((size_t)b << 15) + ((size_t)(uh * 64) << 8) + v4;
    float4* o = out + ((size_t)bt << 15) + ((size_t)(uh * 64) << 8) + v4;
    #pragma unroll 4
    for (int u = 0; u < 64; ++u) {
        o[(size_t)u << 8] = f4add(ye, yp[(size_t)u << 8]);
    }
}

extern "C" void kernel_launch(void* const* d_in, const int* in_sizes, int n_in,
                              void* d_out, int out_size, void* d_ws, size_t ws_size,
                              hipStream_t stream)
{
    const float* pred = (const float*)d_in[0];  // [2,128,512]
    const float* enc  = (const float*)d_in[1];  // [2,512,512]
    const float* W0   = (const float*)d_in[2];  // [512,512]
    const float* b0   = (const float*)d_in[3];  // [512]
    const float* W1   = (const float*)d_in[4];  // [512,1024]
    const float* b1   = (const float*)d_in[5];  // [1024]
    float* out = (float*)d_out;                 // [2,512,128,1024] fp32

    const int D = 512, H = 512, V = 1024;
    const int Mrows = 1280;                     // 1024 enc + 256 pred

    float* P0  = (float*)d_ws;                       // [1280][512]
    float* P1  = P0  + (size_t)Mrows * H;            // [1280][512]
    float* Q0  = P1  + (size_t)Mrows * H;            // [1280][1024]
    float* Q1  = Q0  + (size_t)Mrows * V;            // [1280][1024]
    float* ypF = Q1  + (size_t)Mrows * V;            // [256][1024]

    // P0+P1 = [enc;pred] @ W0   (split-K=2, no bias)
    gemm_sk<0><<<dim3(H / BN, Mrows / BM, 2), 256, 0, stream>>>(
        enc, pred, nullptr, W0, P0, P1, H, D, D / 2);

    // Q0+Q1 = (P0+P1 [+b0 on pred rows]) @ W1   (split-K=2, no b1)
    gemm_sk<1><<<dim3(V / BN, Mrows / BM, 2), 256, 0, stream>>>(
        P0, P1, b0, W1, Q0, Q1, V, H, H / 2);

    // ypF = Q0+Q1+b1 for the 256 pred rows (1 MB)
    finalize_yp<<<256, 256, 0, stream>>>(
        (const float4*)Q0, (const float4*)Q1, (const float4*)b1, (float4*)ypF);

    // out = ye + yp   (536 MB write)
    bcast_add<<<2048, 256, 0, stream>>>(
        (const float4*)Q0, (const float4*)Q1, (const float4*)ypF, (float4*)out);
}